// Round 1
// baseline (102.227 us; speedup 1.0000x reference)
//
#include <hip/hip_runtime.h>

// FidelityModelWithSAE: out[m] = energy[m] + sum_{atoms a in mol m} sae[numbers[a]+200]
// numbers in [0,119) -> gather index in [200,318]; mol_idx is SORTED.
//
// Strategy: memory-bound (64.5 MB fixed traffic, ~10.3 us floor at 6.3 TB/s).
//  - out <- energy via d2d memcpyAsync (graph-safe).
//  - int4 loads of numbers+mol_idx (16B/lane each, coalesced).
//  - SAE window (119 floats) in LDS.
//  - per-lane run merge of 4 contiguous atoms (intra-lane boundary -> direct atomic,
//    ~65K total chip-wide), keep tail run.
//  - cross-lane segmented suffix-reduce over sorted tail keys via 6x shfl_down;
//    only run-head lanes atomicAdd (~150K atomics total over 65K addresses).

#define SAE_WINDOW 119      // numbers in [0,119)
#define SAE_SHIFT  200      // FIDELITY_LEVEL * FIDELITY_OFFSET

__global__ __launch_bounds__(256)
void sae_segsum_kernel(const float* __restrict__ sae,
                       const int*   __restrict__ numbers,
                       const int*   __restrict__ mol_idx,
                       float*       __restrict__ out,
                       int n_vec4, int stride)
{
    __shared__ float s_sae[128];
    const int tid  = threadIdx.x;
    if (tid < SAE_WINDOW) s_sae[tid] = sae[SAE_SHIFT + tid];
    __syncthreads();

    const int lane = tid & 63;
    const int gtid = blockIdx.x * blockDim.x + tid;

    const int4* __restrict__ num4 = (const int4*)numbers;
    const int4* __restrict__ mol4 = (const int4*)mol_idx;

    const int iters = (n_vec4 + stride - 1) / stride;  // uniform across all lanes

    for (int it = 0; it < iters; ++it) {
        const int i = gtid + it * stride;
        int   key = -1;       // invalid marker for out-of-range lanes
        float val = 0.0f;

        if (i < n_vec4) {
            const int4 n = num4[i];
            const int4 m = mol4[i];
            const float v0 = s_sae[n.x];
            const float v1 = s_sae[n.y];
            const float v2 = s_sae[n.z];
            const float v3 = s_sae[n.w];

            // intra-lane run-length merge over 4 contiguous (sorted) mol ids
            int cur = m.x; float acc = v0;
            if (m.y == cur) acc += v1; else { atomicAdd(&out[cur], acc); cur = m.y; acc = v1; }
            if (m.z == cur) acc += v2; else { atomicAdd(&out[cur], acc); cur = m.z; acc = v2; }
            if (m.w == cur) acc += v3; else { atomicAdd(&out[cur], acc); cur = m.w; acc = v3; }
            key = cur; val = acc;   // tail run kept for cross-lane merge
        }

        // cross-lane segmented suffix reduce: tail keys are non-decreasing across
        // the wave; after 6 steps each run-head lane holds its full run sum.
        #pragma unroll
        for (int d = 1; d < 64; d <<= 1) {
            const int   okey = __shfl_down(key, d, 64);
            const float oval = __shfl_down(val, d, 64);
            if ((lane + d) < 64 && okey == key) val += oval;
        }
        const int pkey = __shfl_up(key, 1, 64);
        if (key >= 0 && (lane == 0 || pkey != key)) {
            atomicAdd(&out[key], val);
        }
    }
}

// Fallback for a non-multiple-of-4 atom tail (not hit at N_ATOMS = 2^23).
__global__ void sae_tail_kernel(const float* __restrict__ sae,
                                const int*   __restrict__ numbers,
                                const int*   __restrict__ mol_idx,
                                float*       __restrict__ out,
                                int start, int n_atoms)
{
    int i = start + blockIdx.x * blockDim.x + threadIdx.x;
    if (i < n_atoms) {
        atomicAdd(&out[mol_idx[i]], sae[numbers[i] + SAE_SHIFT]);
    }
}

extern "C" void kernel_launch(void* const* d_in, const int* in_sizes, int n_in,
                              void* d_out, int out_size, void* d_ws, size_t ws_size,
                              hipStream_t stream) {
    const float* energy  = (const float*)d_in[0];   // [N_MOL]
    const float* sae     = (const float*)d_in[1];   // [518]
    const int*   numbers = (const int*)d_in[2];     // [N_ATOMS]
    const int*   mol_idx = (const int*)d_in[3];     // [N_ATOMS]
    float*       out     = (float*)d_out;           // [N_MOL]

    const int n_atoms = in_sizes[2];
    const int n_vec4  = n_atoms >> 2;

    // out <- energy (stream-ordered; atomics below accumulate on top)
    hipMemcpyAsync(out, energy, (size_t)out_size * sizeof(float),
                   hipMemcpyDeviceToDevice, stream);

    const int block  = 256;
    const int grid   = 2048;               // 8 blocks/CU -> full 32-wave occupancy
    const int stride = grid * block;       // 524288 threads; 2^21 int4s -> 4 iters

    sae_segsum_kernel<<<grid, block, 0, stream>>>(sae, numbers, mol_idx, out,
                                                  n_vec4, stride);

    const int rem = n_atoms & 3;
    if (rem) {  // size-dependent (constant per problem), graph-safe
        sae_tail_kernel<<<1, 64, 0, stream>>>(sae, numbers, mol_idx, out,
                                              n_vec4 << 2, n_atoms);
    }
}